// Round 4
// baseline (140.592 us; speedup 1.0000x reference)
//
#include <hip/hip_runtime.h>
#include <hip/hip_bf16.h>

// Fused windowed attention + FC projection for MI355X (gfx950).
// One block per (batch, window): 256 threads = 4 waves, 2 heads per wave.
// R4: all global reads coalesced. Q/K tiles loaded token-sliced (128B
// segments) + shfl-redistributed into MFMA fragments; V staged to LDS
// via coalesced loads + XOR-swizzled transpose writes (bank-conflict-free).
// Swapped-operand attention (S^T = K*Q^T), P^T built by shuffles, no P LDS.

typedef __attribute__((ext_vector_type(8))) short bf8;   // 8 bf16 = 4 VGPRs
typedef __attribute__((ext_vector_type(4))) float f4;    // MFMA C/D

#define SCALE 0.17677669529663687f                 // 1/sqrt(32)
#define CC (SCALE * 1.4426950408889634f)           // SCALE * log2(e)

static __device__ __forceinline__ unsigned short f2bf(float x) {
  unsigned u = __float_as_uint(x);
  u += 0x7FFFu + ((u >> 16) & 1u);
  return (unsigned short)(u >> 16);
}
static __device__ __forceinline__ unsigned pk2(float a, float b) {
  return (unsigned)f2bf(a) | ((unsigned)f2bf(b) << 16);
}
union FragU { unsigned u[4]; bf8 v; };

static __device__ __forceinline__ bf8 load_bf8_f32(const float* __restrict__ p) {
  float4 a = *(const float4*)p;
  float4 b = *(const float4*)(p + 4);
  FragU f;
  f.u[0] = pk2(a.x, a.y);
  f.u[1] = pk2(a.z, a.w);
  f.u[2] = pk2(b.x, b.y);
  f.u[3] = pk2(b.z, b.w);
  return f.v;
}

__global__ void wcvt(const float* __restrict__ W, unsigned short* __restrict__ Wb) {
  const int i = (blockIdx.x * 256 + threadIdx.x) * 4;
  float4 w = *(const float4*)(W + i);
  ushort4 o;
  o.x = f2bf(w.x); o.y = f2bf(w.y); o.z = f2bf(w.z); o.w = f2bf(w.w);
  *(ushort4*)(Wb + i) = o;
}

template <bool WB16>
__global__ __launch_bounds__(256, 4) void win_attn_fc(
    const float* __restrict__ q, const float* __restrict__ k,
    const float* __restrict__ v, const void* __restrict__ Wp,
    float* __restrict__ out) {
  __shared__ unsigned short smem[16896];   // 33792 B: inter[64][264]; VT aliased
  const int tid  = threadIdx.x;
  const int wave = tid >> 6;
  const int lane = tid & 63;
  const int g    = lane >> 4;   // 0..3
  const int c16  = lane & 15;   // 0..15

  const int blk = blockIdx.x;
  const int b   = blk >> 8;          // 256 windows per batch
  const int wy  = (blk >> 4) & 15;
  const int wx  = blk & 15;
  const long tokbase = (long)b * 16384 + (long)(wy * 8) * 128 + wx * 8;

  unsigned short* VT = smem + wave * 2304;  // [32 ch][72 tok] bf16, XOR-swizzled

  // packed bf16 attention outputs: [head][dt][tiq][word], word w = rows 2w,2w+1
  unsigned opk[2][2][4][2];

  const int  srcA  = c16 + ((g & 1) << 5);  // PV shuffle source lane
  const bool hi    = (g >> 1) != 0;         // selects tj = 2kt+1 source register
  const int  srcQK = 4 * c16 + g;           // Q/K redistribution source lane

  // coalesced-load lane roles
  const int qk_tok = lane >> 2;             // 0..15 within-tile token
  const int qk_cg  = lane & 3;              // 8-ch chunk
  const int v_tcol = lane >> 3;             // 0..7 token col
  const int v_cg   = lane & 7;              // 4-ch chunk

  #pragma unroll
  for (int hh = 0; hh < 2; ++hh) {
    const int h = wave * 2 + hh;

    // ---- stage V^T coalesced: instr i covers tokens of image-row i ----
    // write VT[c][tok ^ (v_cg<<3)]  (XOR swizzle -> conflict-free writes,
    // b128 reads stay contiguous since swizzle permutes 8-token blocks)
    #pragma unroll
    for (int i = 0; i < 8; ++i) {
      const long r = tokbase + i * 128 + v_tcol;
      float4 vv = *(const float4*)(v + r * 256 + h * 32 + v_cg * 4);
      const int tswz = 8 * (i ^ v_cg) + v_tcol;
      VT[(4*v_cg + 0) * 72 + tswz] = f2bf(vv.x);
      VT[(4*v_cg + 1) * 72 + tswz] = f2bf(vv.y);
      VT[(4*v_cg + 2) * 72 + tswz] = f2bf(vv.z);
      VT[(4*v_cg + 3) * 72 + tswz] = f2bf(vv.w);
    }

    // ---- Q,K fragments: coalesced token-sliced load + 4-shfl redistribute ----
    bf8 qf[4], kf[4];
    #pragma unroll
    for (int t = 0; t < 4; ++t) {
      const int sm = 16 * t + qk_tok;
      const long sr = tokbase + (sm >> 3) * 128 + (sm & 7);
      {
        const float* p = q + sr * 256 + h * 32 + qk_cg * 8;
        float4 a = *(const float4*)p, bb = *(const float4*)(p + 4);
        unsigned u0 = pk2(a.x, a.y), u1 = pk2(a.z, a.w);
        unsigned u2 = pk2(bb.x, bb.y), u3 = pk2(bb.z, bb.w);
        FragU f;
        f.u[0] = __shfl(u0, srcQK); f.u[1] = __shfl(u1, srcQK);
        f.u[2] = __shfl(u2, srcQK); f.u[3] = __shfl(u3, srcQK);
        qf[t] = f.v;
      }
      {
        const float* p = k + sr * 256 + h * 32 + qk_cg * 8;
        float4 a = *(const float4*)p, bb = *(const float4*)(p + 4);
        unsigned u0 = pk2(a.x, a.y), u1 = pk2(a.z, a.w);
        unsigned u2 = pk2(bb.x, bb.y), u3 = pk2(bb.z, bb.w);
        FragU f;
        f.u[0] = __shfl(u0, srcQK); f.u[1] = __shfl(u1, srcQK);
        f.u[2] = __shfl(u2, srcQK); f.u[3] = __shfl(u3, srcQK);
        kf[t] = f.v;
      }
    }

    #pragma unroll
    for (int ti = 0; ti < 4; ++ti) {
      // ---- S^T tiles: rows k = 16tj+4g+r, col q = 16ti+c16 ----
      f4 st[4];
      #pragma unroll
      for (int tj = 0; tj < 4; ++tj) {
        f4 z = {0.f, 0.f, 0.f, 0.f};
        st[tj] = __builtin_amdgcn_mfma_f32_16x16x32_bf16(kf[tj], qf[ti], z, 0, 0, 0);
      }
      // ---- softmax over k for q=16ti+c16 (16 local vals + 2 shfl) ----
      float mx = st[0][0];
      #pragma unroll
      for (int tj = 0; tj < 4; ++tj)
        #pragma unroll
        for (int r = 0; r < 4; ++r) mx = fmaxf(mx, st[tj][r]);
      mx = fmaxf(mx, __shfl_xor(mx, 16));
      mx = fmaxf(mx, __shfl_xor(mx, 32));
      const float mm = mx * CC;
      float pe[4][4];
      float ds = 0.f;
      #pragma unroll
      for (int tj = 0; tj < 4; ++tj)
        #pragma unroll
        for (int r = 0; r < 4; ++r) {
          float p = exp2f(st[tj][r] * CC - mm);
          pe[tj][r] = p;
          ds += p;
        }
      ds += __shfl_xor(ds, 16);
      ds += __shfl_xor(ds, 32);
      const float rc = 1.0f / ds;
      // pack normalized P as bf16 pairs: PW[tj][w] = rows 4g+2w, 4g+2w+1
      unsigned PW[4][2];
      #pragma unroll
      for (int tj = 0; tj < 4; ++tj) {
        PW[tj][0] = pk2(pe[tj][0] * rc, pe[tj][1] * rc);
        PW[tj][1] = pk2(pe[tj][2] * rc, pe[tj][3] * rc);
      }
      // ---- O^T tiles (dt, ti) = sum_kt V^T_frag x P^T_frag ----
      f4 acc0 = {0.f, 0.f, 0.f, 0.f};
      f4 acc1 = {0.f, 0.f, 0.f, 0.f};
      #pragma unroll
      for (int kt = 0; kt < 2; ++kt) {
        unsigned a0 = __shfl(PW[2*kt  ][0], srcA);
        unsigned a1 = __shfl(PW[2*kt  ][1], srcA);
        unsigned a2 = __shfl(PW[2*kt  ][0], srcA + 16);
        unsigned a3 = __shfl(PW[2*kt  ][1], srcA + 16);
        unsigned b0 = __shfl(PW[2*kt+1][0], srcA);
        unsigned b1 = __shfl(PW[2*kt+1][1], srcA);
        unsigned b2 = __shfl(PW[2*kt+1][0], srcA + 16);
        unsigned b3 = __shfl(PW[2*kt+1][1], srcA + 16);
        FragU pf;
        pf.u[0] = hi ? b0 : a0;
        pf.u[1] = hi ? b1 : a1;
        pf.u[2] = hi ? b2 : a2;
        pf.u[3] = hi ? b3 : a3;
        // swizzled V^T reads (contiguous b128; block index XORed)
        bf8 vf0 = *(const bf8*)(VT + (c16     ) * 72 + 8 * ((4*kt + g) ^ (c16 >> 2)));
        bf8 vf1 = *(const bf8*)(VT + (16 + c16) * 72 + 8 * ((4*kt + g) ^ (4 + (c16 >> 2))));
        acc0 = __builtin_amdgcn_mfma_f32_16x16x32_bf16(vf0, pf.v, acc0, 0, 0, 0);
        acc1 = __builtin_amdgcn_mfma_f32_16x16x32_bf16(vf1, pf.v, acc1, 0, 0, 0);
      }
      opk[hh][0][ti][0] = pk2(acc0[0], acc0[1]);
      opk[hh][0][ti][1] = pk2(acc0[2], acc0[3]);
      opk[hh][1][ti][0] = pk2(acc1[0], acc1[1]);
      opk[hh][1][ti][1] = pk2(acc1[2], acc1[3]);
    }
  }

  // ---- assemble inter[64 tok][264 ch] bf16 (aliases VT -> barrier first) ----
  __syncthreads();
  unsigned short* inter = smem;
  #pragma unroll
  for (int hh = 0; hh < 2; ++hh)
    #pragma unroll
    for (int dt = 0; dt < 2; ++dt)
      #pragma unroll
      for (int ti = 0; ti < 4; ++ti) {
        const int addr = (16*ti + c16) * 264 + (wave*2 + hh) * 32 + 16*dt + 4*g;
        uint2 wv;
        wv.x = opk[hh][dt][ti][0];
        wv.y = opk[hh][dt][ti][1];
        *(uint2*)(inter + addr) = wv;   // 8B-aligned
      }
  __syncthreads();

  // ---- FC: out[tok][64w..64w+63] = inter[64][256] @ W^T ----
  f4 acc[4][4];
  #pragma unroll
  for (int mt = 0; mt < 4; ++mt)
    #pragma unroll
    for (int nt = 0; nt < 4; ++nt) {
      f4 z = {0.f, 0.f, 0.f, 0.f};
      acc[mt][nt] = z;
    }
  const float* Wf          = (const float*)Wp;
  const unsigned short* Wb = (const unsigned short*)Wp;
  #pragma unroll
  for (int ks = 0; ks < 8; ++ks) {
    bf8 af[4], wf[4];
    #pragma unroll
    for (int mt = 0; mt < 4; ++mt)
      af[mt] = *(const bf8*)(inter + (16*mt + c16) * 264 + 32*ks + 8*g);
    #pragma unroll
    for (int nt = 0; nt < 4; ++nt) {
      const long widx = (long)(64*wave + 16*nt + c16) * 256 + 32*ks + 8*g;
      if (WB16) wf[nt] = *(const bf8*)(Wb + widx);
      else      wf[nt] = load_bf8_f32(Wf + widx);
    }
    #pragma unroll
    for (int mt = 0; mt < 4; ++mt)
      #pragma unroll
      for (int nt = 0; nt < 4; ++nt)
        acc[mt][nt] = __builtin_amdgcn_mfma_f32_16x16x32_bf16(af[mt], wf[nt], acc[mt][nt], 0, 0, 0);
  }

  // ---- epilogue: scatter back through window merge, fp32 stores ----
  // (64B-aligned 64B segments per 16 lanes: full-line writes, OK uncoalesced-wise)
  #pragma unroll
  for (int mt = 0; mt < 4; ++mt) {
    #pragma unroll
    for (int r = 0; r < 4; ++r) {
      const int m = 16*mt + 4*g + r;
      const long row = tokbase + (m >> 3) * 128 + (m & 7);
      float* op = out + row * 256 + 64*wave + c16;
      #pragma unroll
      for (int nt = 0; nt < 4; ++nt)
        op[16*nt] = acc[mt][nt][r];
    }
  }
}

extern "C" void kernel_launch(void* const* d_in, const int* in_sizes, int n_in,
                              void* d_out, int out_size, void* d_ws, size_t ws_size,
                              hipStream_t stream) {
  const float* q = (const float*)d_in[0];
  const float* k = (const float*)d_in[1];
  const float* v = (const float*)d_in[2];
  const float* W = (const float*)d_in[3];
  float* out = (float*)d_out;
  const int B = in_sizes[0] / (16384 * 256);
  const size_t wbytes = 65536 * sizeof(unsigned short);
  if (ws_size >= wbytes) {
    wcvt<<<dim3(64), dim3(256), 0, stream>>>(W, (unsigned short*)d_ws);
    win_attn_fc<true><<<dim3(B * 256), dim3(256), 0, stream>>>(q, k, v, d_ws, out);
  } else {
    win_attn_fc<false><<<dim3(B * 256), dim3(256), 0, stream>>>(q, k, v, W, out);
  }
}